// Round 1
// 1200.010 us; speedup vs baseline: 1.3690x; 1.3690x over previous
//
#include <hip/hip_runtime.h>
#include <stdint.h>

#define NB 256  // persistent blocks == CUs
typedef unsigned long long u64;

// ---------- fast math ----------
__device__ __forceinline__ float sigm(float x) {
    return 1.f / (1.f + __expf(-x));
}
__device__ __forceinline__ float tanh_fast(float x) {
    // 1 - 2/(e^{2x}+1): monotone, correct limits at +-inf
    return 1.f - 2.f / (__expf(2.f * x) + 1.f);
}

// ---------- fence-free dataflow sync ----------
// Message word = {tag (hi 32) | f32 payload (lo 32)}. Agent-scope atomics go
// to the coherent point (LLC): no buffer_wbl2 / buffer_inv fences, caches
// (W in AGPRs, Gx in L2) stay warm. Exact-tag match makes double-buffer
// reuse safe: publish(t+1) => consumed all t => all published t => all
// consumed t-1 => overwriting t-1 words is race-free.
__device__ __forceinline__ u64 aload(u64* p) {
    return __hip_atomic_load(p, __ATOMIC_RELAXED, __HIP_MEMORY_SCOPE_AGENT);
}
__device__ __forceinline__ void astore(u64* p, u64 v) {
    __hip_atomic_store(p, v, __ATOMIC_RELAXED, __HIP_MEMORY_SCOPE_AGENT);
}
// Poll 4 consecutive message words until all carry `tag`; write payloads to dst.
__device__ __forceinline__ void poll4(u64* m, unsigned tag, float* dst) {
    u64 v0, v1, v2, v3;
    for (;;) {
        v0 = aload(m + 0);
        v1 = aload(m + 1);
        v2 = aload(m + 2);
        v3 = aload(m + 3);
        if ((unsigned)(v0 >> 32) == tag && (unsigned)(v1 >> 32) == tag &&
            (unsigned)(v2 >> 32) == tag && (unsigned)(v3 >> 32) == tag)
            break;
        __builtin_amdgcn_s_sleep(1);
    }
    dst[0] = __uint_as_float((unsigned)v0);
    dst[1] = __uint_as_float((unsigned)v1);
    dst[2] = __uint_as_float((unsigned)v2);
    dst[3] = __uint_as_float((unsigned)v3);
}

// ---------- kernel G: Gx[t][j] = emb[idx[t]] . W_ih[j] + b_ih[j] + b_hh[j] ----------
template <int TT>
__global__ __launch_bounds__(256) void gates_x_gemm(
    const int* __restrict__ idx, const float* __restrict__ emb,
    const float* __restrict__ Wih, const float* __restrict__ bih,
    const float* __restrict__ bhh, float* __restrict__ Gx) {
    __shared__ float As[TT][36];
    __shared__ float Ws[32][68];  // [k][j], padded
    const int tid = threadIdx.x;
    const int jt = blockIdx.x * 64;
    const int t0 = blockIdx.y * TT;
    constexpr int TPT = TT / 16;
    const int tx = tid & 15, ty = tid >> 4;
    float acc[TPT][4];
#pragma unroll
    for (int a = 0; a < TPT; ++a)
#pragma unroll
        for (int q = 0; q < 4; ++q) acc[a][q] = 0.f;

    for (int k0 = 0; k0 < 1024; k0 += 32) {
        if constexpr (TT == 32) {
            int t = tid >> 3, kq = (tid & 7) * 4;
            int row = idx[t0 + t];
            float4 v = *(const float4*)(emb + (size_t)row * 1024 + k0 + kq);
            *(float4*)&As[t][kq] = v;
        } else {
            int t = tid >> 4, kq = (tid & 15) * 2;
            int row = idx[t0 + t];
            float2 v = *(const float2*)(emb + (size_t)row * 1024 + k0 + kq);
            *(float2*)&As[t][kq] = v;
        }
        {
            int j = tid >> 3, kq = (tid & 7) * 4;
            float4 w0 = *(const float4*)(Wih + (size_t)(jt + j) * 1024 + k0 + kq);
            float4 w1 = *(const float4*)(Wih + (size_t)(jt + j + 32) * 1024 + k0 + kq);
            const float* p0 = (const float*)&w0;
            const float* p1 = (const float*)&w1;
#pragma unroll
            for (int c = 0; c < 4; ++c) {
                Ws[kq + c][j] = p0[c];
                Ws[kq + c][j + 32] = p1[c];
            }
        }
        __syncthreads();
#pragma unroll
        for (int kk = 0; kk < 32; kk += 4) {
            float4 av[TPT];
#pragma unroll
            for (int tt = 0; tt < TPT; ++tt)
                av[tt] = *(float4*)&As[ty * TPT + tt][kk];
#pragma unroll
            for (int c = 0; c < 4; ++c) {
                float4 wv = *(float4*)&Ws[kk + c][tx * 4];
#pragma unroll
                for (int tt = 0; tt < TPT; ++tt) {
                    const float* ap = (const float*)&av[tt];
                    float a = ap[c];
                    acc[tt][0] += a * wv.x;
                    acc[tt][1] += a * wv.y;
                    acc[tt][2] += a * wv.z;
                    acc[tt][3] += a * wv.w;
                }
            }
        }
        __syncthreads();
    }
    int j = jt + tx * 4;
    float4 bi = *(const float4*)(bih + j);
    float4 bh = *(const float4*)(bhh + j);
#pragma unroll
    for (int tt = 0; tt < TPT; ++tt) {
        int t = t0 + ty * TPT + tt;
        float4 r;
        r.x = acc[tt][0] + bi.x + bh.x;
        r.y = acc[tt][1] + bi.y + bh.y;
        r.z = acc[tt][2] + bi.z + bh.z;
        r.w = acc[tt][3] + bi.w + bh.w;
        *(float4*)(Gx + (size_t)t * 8192 + j) = r;
    }
}

// ---------- kernel P: persistent LSTM scans + MLP head ----------
// 256 blocks x 512 threads; block b owns h rows [b*8, b*8+8) -> 32 gate rows.
// W_hh slice kept in REGISTERS (f32): thread (w,l) holds, for rows rl=w*4+r,
// k in {q*256 + l*4 .. +3}, q=0..7  -> 4x8 float4 = 128 VGPRs (AGPR file).
// Inter-block sync: tag+payload atomic words, no fences, no barriers.
__global__ __launch_bounds__(512, 2) void lstm_mlp_persistent(
    const float* __restrict__ Whh_t, const float* __restrict__ Whh_a,
    const float* __restrict__ Gxt, const float* __restrict__ Gxa,
    const float* __restrict__ W1, const float* __restrict__ b1,
    const float* __restrict__ W2, const float* __restrict__ b2,
    const float* __restrict__ W3, const float* __restrict__ b3,
    u64* msg_t, u64* msg_a, float* out) {
    // 84 KB pad forces 1 block/CU so all 256 blocks are co-resident (sync
    // safety); only the first 4096 floats are used for h staging.
    __shared__ float h_lds[21504];
    __shared__ float part_final[32];
    __shared__ float gsum[32];
    __shared__ float cl[8];
    const int tid = threadIdx.x;
    const int b = blockIdx.x;
    const int w = tid >> 6, l = tid & 63;

    for (int scan = 0; scan < 2; ++scan) {
        const float* Whh = scan ? Whh_a : Whh_t;
        const float* Gx = scan ? Gxa : Gxt;
        u64* msg = scan ? msg_a : msg_t;
        const int T = scan ? 16 : 128;

        float4 wreg[4][8];
#pragma unroll
        for (int r = 0; r < 4; ++r) {
            const int rl = w * 4 + r;
            const int j = (rl >> 3) * 2048 + b * 8 + (rl & 7);
            const float* wrow = Whh + (size_t)j * 2048 + l * 4;
#pragma unroll
            for (int q = 0; q < 8; ++q) wreg[r][q] = *(const float4*)(wrow + q * 256);
        }
        if (tid < 8) cl[tid] = 0.f;

        for (int t = 0; t < T; ++t) {
            float gx;
            if (tid < 32)  // prefetch this step's x-gates early (plain load, L2-warm)
                gx = Gx[(size_t)t * 8192 + (tid >> 3) * 2048 + b * 8 + (tid & 7)];
            if (t == 0) {
                *(float4*)(h_lds + tid * 4) = float4{0.f, 0.f, 0.f, 0.f};
            } else {
                // wait for h[t] (tag t) and stage straight into LDS
                poll4(msg + (t & 1) * 2048 + tid * 4, (unsigned)t, h_lds + tid * 4);
            }
            __syncthreads();
            float4 hreg[8];
#pragma unroll
            for (int q = 0; q < 8; ++q) hreg[q] = *(float4*)(h_lds + q * 256 + l * 4);
            float acc[4];
#pragma unroll
            for (int r = 0; r < 4; ++r) {
                float a = 0.f;
#pragma unroll
                for (int q = 0; q < 8; ++q) {
                    a += wreg[r][q].x * hreg[q].x;
                    a += wreg[r][q].y * hreg[q].y;
                    a += wreg[r][q].z * hreg[q].z;
                    a += wreg[r][q].w * hreg[q].w;
                }
                acc[r] = a;
            }
#pragma unroll
            for (int r = 0; r < 4; ++r) {  // wave butterfly per row
                float a = acc[r];
#pragma unroll
                for (int off = 32; off; off >>= 1) a += __shfl_xor(a, off, 64);
                if (l == 0) part_final[w * 4 + r] = a;
            }
            __syncthreads();
            // wave 0 only below: in-order LDS ops within a wave, no extra sync
            if (tid < 32) gsum[tid] = part_final[tid] + gx;
            if (tid < 8) {
                float si = sigm(gsum[tid]);
                float sf = sigm(gsum[8 + tid]);
                float tg = tanh_fast(gsum[16 + tid]);
                float so = sigm(gsum[24 + tid]);
                float c = sf * cl[tid] + si * tg;
                cl[tid] = c;
                float hval = so * tanh_fast(c);
                // publish h[t+1]: tag t+1, payload = exact f32 bits
                astore(msg + ((t + 1) & 1) * 2048 + b * 8 + tid,
                       ((u64)(unsigned)(t + 1) << 32) | (u64)__float_as_uint(hval));
            }
            // no grid barrier: next step's poll is the sync
        }
    }

    // ---- MLP head: summary = [h_title(2048), h_authors(2048)] ----
    // title final h has tag 128 in msg_t[buf 0]; authors tag 16 in msg_a[buf 0]
    poll4(msg_t + tid * 4, 128u, h_lds + tid * 4);
    poll4(msg_a + tid * 4, 16u, h_lds + 2048 + tid * 4);
    __syncthreads();
    {  // h1 = relu(W1 . summary + b1): row j per wave; publish as tag 129
        const int j = b * 8 + w;
        const float* wr = W1 + (size_t)j * 4096;
        float acc = 0.f;
#pragma unroll
        for (int i = 0; i < 16; ++i) {
            float4 wv = *(const float4*)(wr + i * 256 + l * 4);
            float4 hv = *(const float4*)(h_lds + i * 256 + l * 4);
            acc += wv.x * hv.x + wv.y * hv.y + wv.z * hv.z + wv.w * hv.w;
        }
#pragma unroll
        for (int off = 32; off; off >>= 1) acc += __shfl_xor(acc, off, 64);
        if (l == 0) {
            float h1 = fmaxf(acc + b1[j], 0.f);
            astore(msg_t + 2048 + j, (129ull << 32) | (u64)__float_as_uint(h1));
        }
    }
    __syncthreads();  // all summary reads done before h_lds overwrite
    poll4(msg_t + 2048 + tid * 4, 129u, h_lds + tid * 4);
    __syncthreads();
    {  // h2 = relu(W2 . h1 + b2): publish as tag 130
        const int j = b * 8 + w;
        const float* wr = W2 + (size_t)j * 2048;
        float acc = 0.f;
#pragma unroll
        for (int i = 0; i < 8; ++i) {
            float4 wv = *(const float4*)(wr + i * 256 + l * 4);
            float4 hv = *(const float4*)(h_lds + i * 256 + l * 4);
            acc += wv.x * hv.x + wv.y * hv.y + wv.z * hv.z + wv.w * hv.w;
        }
#pragma unroll
        for (int off = 32; off; off >>= 1) acc += __shfl_xor(acc, off, 64);
        if (l == 0) {
            float h2 = fmaxf(acc + b2[j], 0.f);
            astore(msg_t + j, (130ull << 32) | (u64)__float_as_uint(h2));
        }
    }
    if (b == 0) {  // logits: only block 0 consumes h2
        __syncthreads();  // h1 reads done before h_lds overwrite
        poll4(msg_t + tid * 4, 130u, h_lds + tid * 4);
        __syncthreads();
        if (w < 2) {
            const float* wr = W3 + (size_t)w * 2048;
            float acc = 0.f;
#pragma unroll
            for (int i = 0; i < 8; ++i) {
                float4 wv = *(const float4*)(wr + i * 256 + l * 4);
                float4 hv = *(const float4*)(h_lds + i * 256 + l * 4);
                acc += wv.x * hv.x + wv.y * hv.y + wv.z * hv.z + wv.w * hv.w;
            }
#pragma unroll
            for (int off = 32; off; off >>= 1) acc += __shfl_xor(acc, off, 64);
            if (l == 0) out[w] = acc + b3[w];
        }
    }
}

extern "C" void kernel_launch(void* const* d_in, const int* in_sizes, int n_in,
                              void* d_out, int out_size, void* d_ws,
                              size_t ws_size, hipStream_t stream) {
    const int* x_t = (const int*)d_in[0];
    const int* x_a = (const int*)d_in[1];
    const float* emb_t = (const float*)d_in[2];
    const float* emb_a = (const float*)d_in[3];
    const float* Wih_t = (const float*)d_in[4];
    const float* Whh_t = (const float*)d_in[5];
    const float* bih_t = (const float*)d_in[6];
    const float* bhh_t = (const float*)d_in[7];
    const float* Wih_a = (const float*)d_in[8];
    const float* Whh_a = (const float*)d_in[9];
    const float* bih_a = (const float*)d_in[10];
    const float* bhh_a = (const float*)d_in[11];
    const float* W1 = (const float*)d_in[12];
    const float* b1 = (const float*)d_in[13];
    const float* W2 = (const float*)d_in[14];
    const float* b2 = (const float*)d_in[15];
    const float* W3 = (const float*)d_in[16];
    const float* b3 = (const float*)d_in[17];

    // workspace layout (bytes):
    //   msg_t: 2 x 2048 u64  = 32768
    //   msg_a: 2 x 2048 u64  = 32768
    //   gxt  : 128 x 8192 f32 = 4 MiB
    //   gxa  : 16 x 8192 f32  = 512 KiB
    u64* msg_t = (u64*)d_ws;
    u64* msg_a = (u64*)((char*)d_ws + 32768);
    float* gxt = (float*)((char*)d_ws + 65536);
    float* gxa = (float*)((char*)d_ws + 65536 + 4194304);

    // zero message tags (stale tags from previous replay would alias)
    hipMemsetAsync(d_ws, 0, 65536, stream);
    gates_x_gemm<32><<<dim3(128, 4), 256, 0, stream>>>(x_t, emb_t, Wih_t, bih_t,
                                                       bhh_t, gxt);
    gates_x_gemm<16><<<dim3(128, 1), 256, 0, stream>>>(x_a, emb_a, Wih_a, bih_a,
                                                       bhh_a, gxa);
    lstm_mlp_persistent<<<NB, 512, 0, stream>>>(Whh_t, Whh_a, gxt, gxa, W1, b1,
                                                W2, b2, W3, b3, msg_t, msg_a,
                                                (float*)d_out);
}

// Round 2
// 1163.488 us; speedup vs baseline: 1.4119x; 1.0314x over previous
//
#include <hip/hip_runtime.h>
#include <stdint.h>

#define NB 256  // persistent blocks == CUs
typedef unsigned long long u64;
typedef unsigned uint4v __attribute__((ext_vector_type(4)));

// ---------- fast math ----------
__device__ __forceinline__ float sigm(float x) {
    return 1.f / (1.f + __expf(-x));
}
__device__ __forceinline__ float tanh_fast(float x) {
    // 1 - 2/(e^{2x}+1): monotone, correct limits at +-inf
    return 1.f - 2.f / (__expf(2.f * x) + 1.f);
}

// ---------- fence-free dataflow sync ----------
// Message word = {tag (hi 32) | f32 payload (lo 32)}. Agent-scope stores go
// to the coherent point (LLC): no wbl2/inv fences, caches stay warm.
// Exact-tag match makes double-buffer reuse safe: publish(t+1) => consumed
// all of t => all published t => all consumed t-1 => overwrite is race-free.
__device__ __forceinline__ void astore(u64* p, u64 v) {
    __hip_atomic_store(p, v, __ATOMIC_RELAXED, __HIP_MEMORY_SCOPE_AGENT);
}

// Poll 4 consecutive message words with two 16B L1+L2-bypassing loads
// (sc0 sc1 = coherent-at-LLC read; halves poll transactions vs 4x8B atomics).
// Each 8B word is individually tagged, so 16B tearing is harmless.
__device__ __forceinline__ void poll4v(const u64* m, unsigned tag, float* dst) {
    uint4v x, y;
    for (;;) {
        asm volatile(
            "global_load_dwordx4 %0, %2, off sc0 sc1\n\t"
            "global_load_dwordx4 %1, %3, off sc0 sc1\n\t"
            "s_waitcnt vmcnt(0)"
            : "=&v"(x), "=&v"(y)
            : "v"(m), "v"(m + 2)
            : "memory");
        if (x.y == tag && x.w == tag && y.y == tag && y.w == tag) break;
        __builtin_amdgcn_s_sleep(1);
    }
    // u64 little-endian: lo dword = payload, hi dword = tag
    dst[0] = __uint_as_float(x.x);
    dst[1] = __uint_as_float(x.z);
    dst[2] = __uint_as_float(y.x);
    dst[3] = __uint_as_float(y.z);
}

// ---------- kernel G: Gx[t][j] = emb[idx[t]] . W_ih[j] + b_ih[j] + b_hh[j] ----------
template <int TT>
__global__ __launch_bounds__(256) void gates_x_gemm(
    const int* __restrict__ idx, const float* __restrict__ emb,
    const float* __restrict__ Wih, const float* __restrict__ bih,
    const float* __restrict__ bhh, float* __restrict__ Gx) {
    __shared__ float As[TT][36];
    __shared__ float Ws[32][68];  // [k][j], padded
    const int tid = threadIdx.x;
    const int jt = blockIdx.x * 64;
    const int t0 = blockIdx.y * TT;
    constexpr int TPT = TT / 16;
    const int tx = tid & 15, ty = tid >> 4;
    float acc[TPT][4];
#pragma unroll
    for (int a = 0; a < TPT; ++a)
#pragma unroll
        for (int q = 0; q < 4; ++q) acc[a][q] = 0.f;

    for (int k0 = 0; k0 < 1024; k0 += 32) {
        if constexpr (TT == 32) {
            int t = tid >> 3, kq = (tid & 7) * 4;
            int row = idx[t0 + t];
            float4 v = *(const float4*)(emb + (size_t)row * 1024 + k0 + kq);
            *(float4*)&As[t][kq] = v;
        } else {
            int t = tid >> 4, kq = (tid & 15) * 2;
            int row = idx[t0 + t];
            float2 v = *(const float2*)(emb + (size_t)row * 1024 + k0 + kq);
            *(float2*)&As[t][kq] = v;
        }
        {
            int j = tid >> 3, kq = (tid & 7) * 4;
            float4 w0 = *(const float4*)(Wih + (size_t)(jt + j) * 1024 + k0 + kq);
            float4 w1 = *(const float4*)(Wih + (size_t)(jt + j + 32) * 1024 + k0 + kq);
            const float* p0 = (const float*)&w0;
            const float* p1 = (const float*)&w1;
#pragma unroll
            for (int c = 0; c < 4; ++c) {
                Ws[kq + c][j] = p0[c];
                Ws[kq + c][j + 32] = p1[c];
            }
        }
        __syncthreads();
#pragma unroll
        for (int kk = 0; kk < 32; kk += 4) {
            float4 av[TPT];
#pragma unroll
            for (int tt = 0; tt < TPT; ++tt)
                av[tt] = *(float4*)&As[ty * TPT + tt][kk];
#pragma unroll
            for (int c = 0; c < 4; ++c) {
                float4 wv = *(float4*)&Ws[kk + c][tx * 4];
#pragma unroll
                for (int tt = 0; tt < TPT; ++tt) {
                    const float* ap = (const float*)&av[tt];
                    float a = ap[c];
                    acc[tt][0] += a * wv.x;
                    acc[tt][1] += a * wv.y;
                    acc[tt][2] += a * wv.z;
                    acc[tt][3] += a * wv.w;
                }
            }
        }
        __syncthreads();
    }
    int j = jt + tx * 4;
    float4 bi = *(const float4*)(bih + j);
    float4 bh = *(const float4*)(bhh + j);
#pragma unroll
    for (int tt = 0; tt < TPT; ++tt) {
        int t = t0 + ty * TPT + tt;
        float4 r;
        r.x = acc[tt][0] + bi.x + bh.x;
        r.y = acc[tt][1] + bi.y + bh.y;
        r.z = acc[tt][2] + bi.z + bh.z;
        r.w = acc[tt][3] + bi.w + bh.w;
        *(float4*)(Gx + (size_t)t * 8192 + j) = r;
    }
}

// ---------- kernel P: persistent LSTM scans + MLP head ----------
// 256 blocks x 512 threads; block b owns h indices [b*8, b*8+8).
// Wave w owns ALL FOUR gate rows (i,f,g,o) of h index b*8+w:
//   j_q = q*2048 + b*8 + w, q=0..3.  W_hh slice in registers: wreg[4][8]
//   float4 = 128 VGPRs (thread l holds k = k8*256 + l*4 .. +3).
// After per-row 64-lane butterflies every lane has all 4 gate sums (fp add
// is commutative -> bitwise identical across lanes), so each wave computes
// c,h redundantly in registers and publishes IMMEDIATELY — no second
// barrier, no wave-0 serial tail on the critical path.
__global__ __launch_bounds__(512, 2) void lstm_mlp_persistent(
    const float* __restrict__ Whh_t, const float* __restrict__ Whh_a,
    const float* __restrict__ Gxt, const float* __restrict__ Gxa,
    const float* __restrict__ W1, const float* __restrict__ b1,
    const float* __restrict__ W2, const float* __restrict__ b2,
    const float* __restrict__ W3, const float* __restrict__ b3,
    u64* msg_t, u64* msg_a, float* out) {
    // 84 KB pad forces 1 block/CU so all 256 blocks are co-resident (spin
    // safety); only the first 4096 floats are used (h double-buffer / MLP).
    __shared__ float h_lds[21504];
    const int tid = threadIdx.x;
    const int b = blockIdx.x;
    const int w = tid >> 6, l = tid & 63;

    for (int scan = 0; scan < 2; ++scan) {
        const float* Whh = scan ? Whh_a : Whh_t;
        const float* Gx = scan ? Gxa : Gxt;
        u64* msg = scan ? msg_a : msg_t;
        const int T = scan ? 16 : 128;

        float4 wreg[4][8];
#pragma unroll
        for (int q = 0; q < 4; ++q) {
            const int j = q * 2048 + b * 8 + w;
            const float* wrow = Whh + (size_t)j * 2048 + l * 4;
#pragma unroll
            for (int k8 = 0; k8 < 8; ++k8)
                wreg[q][k8] = *(const float4*)(wrow + k8 * 256);
        }
        float c = 0.f;  // cell state, replicated across the wave's lanes

        for (int t = 0; t < T; ++t) {
            // x-gates for this wave's h index: wave-uniform loads, issued
            // before the poll so their latency hides under it
            float gxv[4];
#pragma unroll
            for (int q = 0; q < 4; ++q)
                gxv[q] = Gx[(size_t)t * 8192 + q * 2048 + b * 8 + w];
            float* hstage = h_lds + (t & 1) * 2048;  // double buffer by t&1
            if (t == 0) {
                *(float4*)(hstage + tid * 4) = float4{0.f, 0.f, 0.f, 0.f};
            } else {
                poll4v(msg + (t & 1) * 2048 + tid * 4, (unsigned)t,
                       hstage + tid * 4);
            }
            __syncthreads();  // the ONLY barrier per step
            float4 hreg[8];
#pragma unroll
            for (int k8 = 0; k8 < 8; ++k8)
                hreg[k8] = *(float4*)(hstage + k8 * 256 + l * 4);
            float acc[4];
#pragma unroll
            for (int q = 0; q < 4; ++q) {
                float a = 0.f;
#pragma unroll
                for (int k8 = 0; k8 < 8; ++k8) {
                    a += wreg[q][k8].x * hreg[k8].x;
                    a += wreg[q][k8].y * hreg[k8].y;
                    a += wreg[q][k8].z * hreg[k8].z;
                    a += wreg[q][k8].w * hreg[k8].w;
                }
                acc[q] = a;
            }
#pragma unroll
            for (int q = 0; q < 4; ++q) {  // butterfly: total lands in ALL lanes
                float a = acc[q];
#pragma unroll
                for (int off = 32; off; off >>= 1) a += __shfl_xor(a, off, 64);
                acc[q] = a;
            }
            // gates, redundantly in every lane (deterministic => consistent)
            float gi = sigm(acc[0] + gxv[0]);
            float gf = sigm(acc[1] + gxv[1]);
            float gg = tanh_fast(acc[2] + gxv[2]);
            float go = sigm(acc[3] + gxv[3]);
            c = gf * c + gi * gg;
            float hval = go * tanh_fast(c);
            if (l == 0)  // publish h[t+1] the moment this wave is done
                astore(msg + ((t + 1) & 1) * 2048 + b * 8 + w,
                       ((u64)(unsigned)(t + 1) << 32) | (u64)__float_as_uint(hval));
        }
    }

    // ---- MLP head: summary = [h_title(2048), h_authors(2048)] ----
    // title final h: tag 128, buffer 0 of msg_t; authors: tag 16, buffer 0
    poll4v(msg_t + tid * 4, 128u, h_lds + tid * 4);
    poll4v(msg_a + tid * 4, 16u, h_lds + 2048 + tid * 4);
    __syncthreads();
    {  // h1 = relu(W1 . summary + b1): row j per wave; publish as tag 129
        const int j = b * 8 + w;
        const float* wr = W1 + (size_t)j * 4096;
        float acc = 0.f;
#pragma unroll
        for (int i = 0; i < 16; ++i) {
            float4 wv = *(const float4*)(wr + i * 256 + l * 4);
            float4 hv = *(const float4*)(h_lds + i * 256 + l * 4);
            acc += wv.x * hv.x + wv.y * hv.y + wv.z * hv.z + wv.w * hv.w;
        }
#pragma unroll
        for (int off = 32; off; off >>= 1) acc += __shfl_xor(acc, off, 64);
        if (l == 0) {
            float h1 = fmaxf(acc + b1[j], 0.f);
            astore(msg_t + 2048 + j, (129ull << 32) | (u64)__float_as_uint(h1));
        }
    }
    __syncthreads();  // all summary reads done before h_lds overwrite
    poll4v(msg_t + 2048 + tid * 4, 129u, h_lds + tid * 4);
    __syncthreads();
    {  // h2 = relu(W2 . h1 + b2): publish as tag 130
        const int j = b * 8 + w;
        const float* wr = W2 + (size_t)j * 2048;
        float acc = 0.f;
#pragma unroll
        for (int i = 0; i < 8; ++i) {
            float4 wv = *(const float4*)(wr + i * 256 + l * 4);
            float4 hv = *(const float4*)(h_lds + i * 256 + l * 4);
            acc += wv.x * hv.x + wv.y * hv.y + wv.z * hv.z + wv.w * hv.w;
        }
#pragma unroll
        for (int off = 32; off; off >>= 1) acc += __shfl_xor(acc, off, 64);
        if (l == 0) {
            float h2 = fmaxf(acc + b2[j], 0.f);
            astore(msg_t + j, (130ull << 32) | (u64)__float_as_uint(h2));
        }
    }
    if (b == 0) {  // logits: only block 0 consumes h2
        __syncthreads();  // h1 reads done before h_lds overwrite
        poll4v(msg_t + tid * 4, 130u, h_lds + tid * 4);
        __syncthreads();
        if (w < 2) {
            const float* wr = W3 + (size_t)w * 2048;
            float acc = 0.f;
#pragma unroll
            for (int i = 0; i < 8; ++i) {
                float4 wv = *(const float4*)(wr + i * 256 + l * 4);
                float4 hv = *(const float4*)(h_lds + i * 256 + l * 4);
                acc += wv.x * hv.x + wv.y * hv.y + wv.z * hv.z + wv.w * hv.w;
            }
#pragma unroll
            for (int off = 32; off; off >>= 1) acc += __shfl_xor(acc, off, 64);
            if (l == 0) out[w] = acc + b3[w];
        }
    }
}

extern "C" void kernel_launch(void* const* d_in, const int* in_sizes, int n_in,
                              void* d_out, int out_size, void* d_ws,
                              size_t ws_size, hipStream_t stream) {
    const int* x_t = (const int*)d_in[0];
    const int* x_a = (const int*)d_in[1];
    const float* emb_t = (const float*)d_in[2];
    const float* emb_a = (const float*)d_in[3];
    const float* Wih_t = (const float*)d_in[4];
    const float* Whh_t = (const float*)d_in[5];
    const float* bih_t = (const float*)d_in[6];
    const float* bhh_t = (const float*)d_in[7];
    const float* Wih_a = (const float*)d_in[8];
    const float* Whh_a = (const float*)d_in[9];
    const float* bih_a = (const float*)d_in[10];
    const float* bhh_a = (const float*)d_in[11];
    const float* W1 = (const float*)d_in[12];
    const float* b1 = (const float*)d_in[13];
    const float* W2 = (const float*)d_in[14];
    const float* b2 = (const float*)d_in[15];
    const float* W3 = (const float*)d_in[16];
    const float* b3 = (const float*)d_in[17];

    // workspace layout (bytes):
    //   msg_t: 2 x 2048 u64  = 32768
    //   msg_a: 2 x 2048 u64  = 32768
    //   gxt  : 128 x 8192 f32 = 4 MiB
    //   gxa  : 16 x 8192 f32  = 512 KiB
    u64* msg_t = (u64*)d_ws;
    u64* msg_a = (u64*)((char*)d_ws + 32768);
    float* gxt = (float*)((char*)d_ws + 65536);
    float* gxa = (float*)((char*)d_ws + 65536 + 4194304);

    // zero message tags (stale tags from a previous replay would alias)
    hipMemsetAsync(d_ws, 0, 65536, stream);
    gates_x_gemm<32><<<dim3(128, 4), 256, 0, stream>>>(x_t, emb_t, Wih_t, bih_t,
                                                       bhh_t, gxt);
    gates_x_gemm<16><<<dim3(128, 1), 256, 0, stream>>>(x_a, emb_a, Wih_a, bih_a,
                                                       bhh_a, gxa);
    lstm_mlp_persistent<<<NB, 512, 0, stream>>>(Whh_t, Whh_a, gxt, gxa, W1, b1,
                                                W2, b2, W3, b3, msg_t, msg_a,
                                                (float*)d_out);
}